// Round 5
// baseline (201.993 us; speedup 1.0000x reference)
//
#include <hip/hip_runtime.h>

typedef unsigned short u16;
typedef unsigned int u32;
typedef unsigned char u8;
typedef unsigned long long u64;

#define GG   512
#define NPG  90
#define NTOT (GG*NPG)
#define NED  921600
#define FIN  90
#define HC   64
#define KP   70
#define AW   23      // packed-A words per row (23*4 = 92 >= 90)
#define AWG  (NPG*AW) // 2070 words per graph

#define SAD  92   // x stride (floats): 16B-aligned rows -> ds_read_b128; 23l mod 32 bijective
#define SP   68   // r1/h2 stride: float4 rows 16B-aligned; 17l mod 32 bijective
#define APW  25   // packed-A LDS stride (words): 25l mod 32 bijective -> conflict-free b32

// wf (f32 weights in ws) layout, float offsets:
#define WF_W1L 0
#define WF_W1R 5760
#define WF_W2L 11520
#define WF_W2R 15616
#define WF_B1  19712
#define WF_B2  19776
#define WF_FOLD 19840
#define WF_ZC  24320
#define WF_FLAG 24321

__device__ __forceinline__ float bf2f(u16 u) {
    union { u32 i; float f; } v; v.i = ((u32)u) << 16; return v.f;
}
__device__ __forceinline__ float bflo(u32 u) {
    union { u32 i; float f; } v; v.i = u << 16; return v.f;
}
__device__ __forceinline__ float bfhi(u32 u) {
    union { u32 i; float f; } v; v.i = u & 0xFFFF0000u; return v.f;
}
__device__ __forceinline__ u16 f2bf(float f) {
    union { float f; u32 i; } v; v.f = f;
    u32 r = (v.i + 0x7FFFu + ((v.i >> 16) & 1u)) >> 16;
    return (u16)r;
}
__device__ __forceinline__ float ldadp(const void* p, long long i, int isf32) {
    return isf32 ? ((const float*)p)[i] : bf2f(((const u16*)p)[i]);
}
// exact cross-lane fetch: uniform lane index -> v_readlane_b32 (SGPR result, no LDS)
__device__ __forceinline__ float rdlane(float v, int lane) {
    return __uint_as_float(__builtin_amdgcn_readlane(__float_as_uint(v), lane));
}

// ---- merged prep: byte-packed dense-A build + weight convert + MLP fold. (unchanged)
__global__ __launch_bounds__(256) void k_pre(
    const u32* __restrict__ xw, const int* __restrict__ ei,
    const void* W1l, const void* W1r, const void* b1,
    const void* W2l, const void* W2r, const void* b2,
    const void* Wl1, const void* bl1, const void* Wl2, const void* bl2,
    u32* __restrict__ A32, float* __restrict__ wf)
{
    __shared__ int sf;
    const int t = threadIdx.x;
    const int b = blockIdx.x;

    if (b < 900) {
        int lane = t & 63;
        u32 v = (lane < 16) ? (u32)ei[lane] : 0u;
        u64 bb = __ballot((lane & 1) && (v != 0));
        bool wide = (bb == 0ull);          // int64: odd (hi) words all zero
        int e0 = b * 1024 + t * 4;
        int s[4], d[4];
        if (wide) {
            uint4 s01 = *(const uint4*)(ei + 2 * e0);
            uint4 s23 = *(const uint4*)(ei + 2 * e0 + 4);
            uint4 d01 = *(const uint4*)(ei + 2 * (NED + e0));
            uint4 d23 = *(const uint4*)(ei + 2 * (NED + e0) + 4);
            s[0] = (int)s01.x; s[1] = (int)s01.z; s[2] = (int)s23.x; s[3] = (int)s23.z;
            d[0] = (int)d01.x; d[1] = (int)d01.z; d[2] = (int)d23.x; d[3] = (int)d23.z;
        } else {
            uint4 ss = *(const uint4*)(ei + e0);
            uint4 dd = *(const uint4*)(ei + NED + e0);
            s[0] = (int)ss.x; s[1] = (int)ss.y; s[2] = (int)ss.z; s[3] = (int)ss.w;
            d[0] = (int)dd.x; d[1] = (int)dd.y; d[2] = (int)dd.z; d[3] = (int)dd.w;
        }
        #pragma unroll
        for (int k = 0; k < 4; ++k) {
            int dk = d[k];
            if ((unsigned)dk >= NTOT) continue;
            int g = (unsigned)dk / NPG;
            int dl = dk - g * NPG;
            int ls = s[k] - g * NPG;
            if ((unsigned)ls >= NPG) continue;
            atomicAdd(&A32[(size_t)g * AWG + dl * AW + (ls >> 2)],
                      1u << (8 * (ls & 3)));
        }
        return;
    }

    if (t < 64) {
        u32 e = (xw[t] >> 7) & 0xFF;       // exponent of low-half-as-bf16
        u64 bb = __ballot(e >= 136);       // impossible for N(0,1)-scale bf16
        if (t == 0) sf = (bb != 0ull) ? 1 : 0;
    }
    __syncthreads();
    const int f32 = sf;

    if (b < 978) {
        int i = (b - 900) * 256 + t;
        if      (i < 5760)  wf[i] = ldadp(W1l, i, f32);
        else if (i < 11520) wf[i] = ldadp(W1r, i - 5760, f32);
        else if (i < 15616) wf[i] = ldadp(W2l, i - 11520, f32);
        else if (i < 19712) wf[i] = ldadp(W2r, i - 15616, f32);
        else if (i < 19776) wf[i] = ldadp(b1, i - 19712, f32);
        else if (i < 19840) wf[i] = ldadp(b2, i - 19776, f32);
        if (b == 900 && t == 0) wf[WF_FLAG] = f32 ? 1.0f : 0.0f;
    } else {
        int m = (b - 978) * 256 + t;
        if (m < 4480) {
            float s = 0.f;
            if (!f32) {
                // vectorized bf16 loads; multiply/add sequence identical to scalar path
                const uint4* Wp = (const uint4*)((const u16*)Wl1 + (size_t)m * HC);
                #pragma unroll
                for (int q = 0; q < 8; ++q) {
                    uint4 v = Wp[q];
                    u32 a0 = v.x, a1 = v.y, a2 = v.z, a3 = v.w;
                    int j = q * 8;
                    s += bflo(a0) * bf2f(((const u16*)Wl2)[j+0]);
                    s += bfhi(a0) * bf2f(((const u16*)Wl2)[j+1]);
                    s += bflo(a1) * bf2f(((const u16*)Wl2)[j+2]);
                    s += bfhi(a1) * bf2f(((const u16*)Wl2)[j+3]);
                    s += bflo(a2) * bf2f(((const u16*)Wl2)[j+4]);
                    s += bfhi(a2) * bf2f(((const u16*)Wl2)[j+5]);
                    s += bflo(a3) * bf2f(((const u16*)Wl2)[j+6]);
                    s += bfhi(a3) * bf2f(((const u16*)Wl2)[j+7]);
                }
            } else {
                for (int j = 0; j < HC; ++j)
                    s += ((const float*)Wl1)[(long long)m * HC + j] * ((const float*)Wl2)[j];
            }
            wf[WF_FOLD + m] = s;
        } else if (m == 4480) {
            float s = ldadp(bl2, 0, f32);
            for (int j = 0; j < HC; ++j)
                s += ldadp(bl1, j, f32) * ldadp(Wl2, j, f32);
            wf[WF_ZC] = s;
        }
    }
}

// ---- fused pipeline: GEMM->Agg made WAVE-LOCAL via v_readlane.
// Wave w's GEMM computes P[rows l,l+64][cols jb_w..jb_w+7] with lane=row; Agg of the
// same wave needs P[k][jb_w+j], which lives in lane (k&63)'s accumulator -> readlane.
// P/P2 never touch LDS; Agg loops have no lgkmcnt dependency; 5 barriers total.
// LDS regions (bytes):
//   As/H2 @0      33120  (x [90][92] during GEMM1; then h2 [90][68])
//   R1    @33120  24480  (r1 [90][68], sole LDS intermediate)
//   Apk   @57600   9000  (packed A bytes [90][25], whole kernel)
//   key/red/ord @66600 ~540
// Barrier ledger:
//   B0: x + Apk staged
//   B1: r1 complete           (x reads done before each wave's r1 write)
//   B2: h2 + s_key complete   (h2 overwrites x region, dead since B1)
//   B3: s_ord complete
//   B4: s_red complete
__global__ __launch_bounds__(512, 4) void k_fused(
    const void* __restrict__ x, const u32* __restrict__ A32,
    const float* __restrict__ wf, void* __restrict__ dout)
{
    __shared__ __align__(16) char smem[67136];
    float* As    = (float*)smem;                 // x during GEMM1
    float* H2    = (float*)smem;                 // h2 (stride SP) after B1
    float* R1    = (float*)(smem + 33120);       // r1 (stride SP)
    u32*   Apk   = (u32*)(smem + 57600);
    float* s_key = (float*)(smem + 66600);
    float* s_red = (float*)(smem + 66960);
    u16*   s_ord = (u16*)(smem + 66992);

    const int g = blockIdx.x;
    const int t = threadIdx.x;
    const bool isf32 = (wf[WF_FLAG] > 0.5f);

    const int l = t & 63;
    const int w = __builtin_amdgcn_readfirstlane(t >> 6);  // wave id, SGPR
    const int jb = w * 8;                                   // wave-uniform slab
    const int row0 = l;
    const bool has2 = (l < NPG - 64);
    const int row1 = has2 ? l + 64 : l;

    // ---- load packed A and stage to LDS ----
    u32 abuf[5];
    {
        const u32* Ag = A32 + (size_t)g * AWG;
        #pragma unroll
        for (int j = 0; j < 5; ++j) {
            int p = t + j * 512;
            abuf[j] = (p < AWG) ? Ag[p] : 0u;
        }
    }

    // ---- stage x -> As (expand bf16 to f32; single GEMM path) ----
    if (isf32) {
        const float* xg = (const float*)x + (size_t)g * 8100;
        for (int p = t; p < 8100; p += 512) {
            int r = p / NPG, c = p - r * NPG;
            As[r * SAD + c] = xg[p];
        }
    } else {
        const u32* xg = (const u32*)((const u16*)x + (size_t)g * 8100);
        for (int p = t; p < 4050; p += 512) {
            int r = p / 45, c = (p - r * 45) * 2;
            u32 v = xg[p];
            As[r * SAD + c]     = bflo(v);
            As[r * SAD + c + 1] = bfhi(v);
        }
    }
    if (t < 180) As[(t >> 1) * SAD + 90 + (t & 1)] = 0.f;  // pad cols -> exact +0
    #pragma unroll
    for (int j = 0; j < 5; ++j) {
        int p = t + j * 512;
        if (p < AWG) {
            int r = p / AW, wc = p - r * AW;
            Apk[r * APW + wc] = abuf[j];
        }
    }
    __syncthreads();  // B0: x + Apk staged

    // ---- GEMM1: P = x@W1l, Q = x@W1r + b1 ; weights wave-uniform (s_load) ----
    float accP[2][8], accQ[2][8];
    {
        const float* bb = wf + WF_B1 + jb;
        #pragma unroll
        for (int j = 0; j < 8; ++j) {
            float bv = bb[j];
            accP[0][j] = 0.f; accP[1][j] = 0.f;
            accQ[0][j] = bv;  accQ[1][j] = bv;
        }
    }
    {
        const float* WL = wf + WF_W1L + jb;
        const float* WR = wf + WF_W1R + jb;
        const float* X0 = As + row0 * SAD;
        const float* X1 = As + row1 * SAD;
        for (int k0 = 0; k0 < 23; ++k0) {   // k=90,91: x=0 -> exact +0 (w reads in-bounds of wf)
            float4 q0 = *(const float4*)(X0 + 4 * k0);
            float4 q1 = *(const float4*)(X1 + 4 * k0);
            float xa0[4] = {q0.x, q0.y, q0.z, q0.w};
            float xa1[4] = {q1.x, q1.y, q1.z, q1.w};
            #pragma unroll
            for (int jj = 0; jj < 4; ++jj) {
                int k = 4 * k0 + jj;
                float wl[8], wr[8];
                #pragma unroll
                for (int j = 0; j < 8; ++j) { wl[j] = WL[k * HC + j]; wr[j] = WR[k * HC + j]; }
                #pragma unroll
                for (int j = 0; j < 8; ++j) {
                    accP[0][j] += xa0[jj] * wl[j]; accQ[0][j] += xa0[jj] * wr[j];
                    accP[1][j] += xa1[jj] * wl[j]; accQ[1][j] += xa1[jj] * wr[j];
                }
            }
        }
    }

    // ---- Agg1 (wave-local, NO barrier): h1 = rc*(A@P) + Q ; P via readlane ----
    float r1v[2][8];
    float rc0, rc1;
    {
        float acc[2][8];
        float asum0 = 0.f, asum1 = 0.f;
        #pragma unroll
        for (int i = 0; i < 2; ++i)
            #pragma unroll
            for (int j = 0; j < 8; ++j) acc[i][j] = 0.f;
        const u32* A0 = Apk + row0 * APW;
        const u32* A1 = Apk + row1 * APW;
        // k = 0..63: P[k][jb+j] = lane k's accP[0][j]
        for (int k0 = 0; k0 < 16; ++k0) {
            u32 w0 = A0[k0], w1 = A1[k0];
            #pragma unroll
            for (int jj = 0; jj < 4; ++jj) {
                int k = 4 * k0 + jj;
                float a0 = (float)((w0 >> (8 * jj)) & 255u);
                float a1 = (float)((w1 >> (8 * jj)) & 255u);
                asum0 += a0; asum1 += a1;
                #pragma unroll
                for (int j = 0; j < 8; ++j) {
                    float pv = rdlane(accP[0][j], k);
                    acc[0][j] += a0 * pv;
                    acc[1][j] += a1 * pv;
                }
            }
        }
        // k = 64..87: P[k][jb+j] = lane (k-64)'s accP[1][j]
        for (int k0 = 16; k0 < 22; ++k0) {
            u32 w0 = A0[k0], w1 = A1[k0];
            #pragma unroll
            for (int jj = 0; jj < 4; ++jj) {
                int k = 4 * k0 + jj;
                float a0 = (float)((w0 >> (8 * jj)) & 255u);
                float a1 = (float)((w1 >> (8 * jj)) & 255u);
                asum0 += a0; asum1 += a1;
                #pragma unroll
                for (int j = 0; j < 8; ++j) {
                    float pv = rdlane(accP[1][j], k - 64);
                    acc[0][j] += a0 * pv;
                    acc[1][j] += a1 * pv;
                }
            }
        }
        {   // tail k = 88, 89 (lanes 24, 25 of accP[1])
            u32 w0 = A0[22], w1 = A1[22];
            #pragma unroll
            for (int jj = 0; jj < 2; ++jj) {
                int k = 88 + jj;
                float a0 = (float)((w0 >> (8 * jj)) & 255u);
                float a1 = (float)((w1 >> (8 * jj)) & 255u);
                asum0 += a0; asum1 += a1;
                #pragma unroll
                for (int j = 0; j < 8; ++j) {
                    float pv = rdlane(accP[1][j], k - 64);
                    acc[0][j] += a0 * pv;
                    acc[1][j] += a1 * pv;
                }
            }
        }
        rc0 = 1.0f / fmaxf(asum0, 1.0f);
        rc1 = 1.0f / fmaxf(asum1, 1.0f);
        #pragma unroll
        for (int i = 0; i < 2; ++i) {
            if (i == 0 || has2) {
                int n = i ? row1 : row0;
                float rc = i ? rc1 : rc0;
                float h[8];
                #pragma unroll
                for (int j = 0; j < 8; ++j) h[j] = fmaf(rc, acc[i][j], accQ[i][j]);
                size_t base = 512 + (size_t)(g * NPG + n) * HC + jb;
                if (isf32) {
                    *(float4*)((float*)dout + base)     = make_float4(h[0],h[1],h[2],h[3]);
                    *(float4*)((float*)dout + base + 4) = make_float4(h[4],h[5],h[6],h[7]);
                } else {
                    uint4 pk;
                    pk.x = (u32)f2bf(h[0]) | ((u32)f2bf(h[1]) << 16);
                    pk.y = (u32)f2bf(h[2]) | ((u32)f2bf(h[3]) << 16);
                    pk.z = (u32)f2bf(h[4]) | ((u32)f2bf(h[5]) << 16);
                    pk.w = (u32)f2bf(h[6]) | ((u32)f2bf(h[7]) << 16);
                    *(uint4*)((u16*)dout + base) = pk;
                }
                #pragma unroll
                for (int j = 0; j < 8; ++j) r1v[i][j] = fmaxf(h[j], 0.f);
            }
        }
    }
    // ---- write r1 -> R1 (region untouched since B0; disjoint from x) ----
    *(float4*)(R1 + row0 * SP + jb)     = make_float4(r1v[0][0], r1v[0][1], r1v[0][2], r1v[0][3]);
    *(float4*)(R1 + row0 * SP + jb + 4) = make_float4(r1v[0][4], r1v[0][5], r1v[0][6], r1v[0][7]);
    if (has2) {
        *(float4*)(R1 + row1 * SP + jb)     = make_float4(r1v[1][0], r1v[1][1], r1v[1][2], r1v[1][3]);
        *(float4*)(R1 + row1 * SP + jb + 4) = make_float4(r1v[1][4], r1v[1][5], r1v[1][6], r1v[1][7]);
    }
    __syncthreads();  // B1: r1 complete (all x reads finished before this)

    // ---- GEMM2: P2 = r1@W2l, Q2 = r1@W2r + b2 ; b128 per-lane-row r1 reads ----
    {
        const float* bb = wf + WF_B2 + jb;
        #pragma unroll
        for (int j = 0; j < 8; ++j) {
            float bv = bb[j];
            accP[0][j] = 0.f; accP[1][j] = 0.f;
            accQ[0][j] = bv;  accQ[1][j] = bv;
        }
    }
    {
        const float* WL = wf + WF_W2L + jb;
        const float* WR = wf + WF_W2R + jb;
        const float* V0 = R1 + row0 * SP;
        const float* V1 = R1 + row1 * SP;
        for (int k0 = 0; k0 < 16; ++k0) {
            float4 q0 = *(const float4*)(V0 + 4 * k0);
            float4 q1 = *(const float4*)(V1 + 4 * k0);
            float va0[4] = {q0.x, q0.y, q0.z, q0.w};
            float va1[4] = {q1.x, q1.y, q1.z, q1.w};
            #pragma unroll
            for (int jj = 0; jj < 4; ++jj) {
                int k = 4 * k0 + jj;
                float wl[8], wr[8];
                #pragma unroll
                for (int j = 0; j < 8; ++j) { wl[j] = WL[k * HC + j]; wr[j] = WR[k * HC + j]; }
                #pragma unroll
                for (int j = 0; j < 8; ++j) {
                    accP[0][j] += va0[jj] * wl[j]; accQ[0][j] += va0[jj] * wr[j];
                    accP[1][j] += va1[jj] * wl[j]; accQ[1][j] += va1[jj] * wr[j];
                }
            }
        }
    }

    // ---- Agg2 (wave-local, NO barrier): h2 = rc*(A@P2) + Q2 ; P2 via readlane ----
    float h2v[2][8];
    {
        float acc[2][8];
        #pragma unroll
        for (int i = 0; i < 2; ++i)
            #pragma unroll
            for (int j = 0; j < 8; ++j) acc[i][j] = 0.f;
        const u32* A0 = Apk + row0 * APW;
        const u32* A1 = Apk + row1 * APW;
        for (int k0 = 0; k0 < 16; ++k0) {
            u32 w0 = A0[k0], w1 = A1[k0];
            #pragma unroll
            for (int jj = 0; jj < 4; ++jj) {
                int k = 4 * k0 + jj;
                float a0 = (float)((w0 >> (8 * jj)) & 255u);
                float a1 = (float)((w1 >> (8 * jj)) & 255u);
                #pragma unroll
                for (int j = 0; j < 8; ++j) {
                    float pv = rdlane(accP[0][j], k);
                    acc[0][j] += a0 * pv;
                    acc[1][j] += a1 * pv;
                }
            }
        }
        for (int k0 = 16; k0 < 22; ++k0) {
            u32 w0 = A0[k0], w1 = A1[k0];
            #pragma unroll
            for (int jj = 0; jj < 4; ++jj) {
                int k = 4 * k0 + jj;
                float a0 = (float)((w0 >> (8 * jj)) & 255u);
                float a1 = (float)((w1 >> (8 * jj)) & 255u);
                #pragma unroll
                for (int j = 0; j < 8; ++j) {
                    float pv = rdlane(accP[1][j], k - 64);
                    acc[0][j] += a0 * pv;
                    acc[1][j] += a1 * pv;
                }
            }
        }
        {   // tail k = 88, 89
            u32 w0 = A0[22], w1 = A1[22];
            #pragma unroll
            for (int jj = 0; jj < 2; ++jj) {
                int k = 88 + jj;
                float a0 = (float)((w0 >> (8 * jj)) & 255u);
                float a1 = (float)((w1 >> (8 * jj)) & 255u);
                #pragma unroll
                for (int j = 0; j < 8; ++j) {
                    float pv = rdlane(accP[1][j], k - 64);
                    acc[0][j] += a0 * pv;
                    acc[1][j] += a1 * pv;
                }
            }
        }
        #pragma unroll
        for (int i = 0; i < 2; ++i) {
            if (i == 0 || has2) {
                int n = i ? row1 : row0;
                float rc = i ? rc1 : rc0;
                #pragma unroll
                for (int j = 0; j < 8; ++j)
                    h2v[i][j] = fmaf(rc, acc[i][j], accQ[i][j]);
                if (w == 7) s_key[n] = h2v[i][7];
            }
        }
    }
    // ---- write h2 -> H2 (x region, dead since B1) ----
    *(float4*)(H2 + row0 * SP + jb)     = make_float4(h2v[0][0], h2v[0][1], h2v[0][2], h2v[0][3]);
    *(float4*)(H2 + row0 * SP + jb + 4) = make_float4(h2v[0][4], h2v[0][5], h2v[0][6], h2v[0][7]);
    if (has2) {
        *(float4*)(H2 + row1 * SP + jb)     = make_float4(h2v[1][0], h2v[1][1], h2v[1][2], h2v[1][3]);
        *(float4*)(H2 + row1 * SP + jb + 4) = make_float4(h2v[1][4], h2v[1][5], h2v[1][6], h2v[1][7]);
    }
    __syncthreads();  // B2: h2 + s_key complete

    // ---- stable descending rank (== stable argsort(-key)) ----
    if (t < NPG) {
        float my = s_key[t];
        int r = 0;
        for (int m2 = 0; m2 < NPG; ++m2) {
            float km = s_key[m2];
            r += (km > my) || (km == my && m2 < t);
        }
        if (r < KP) s_ord[r] = (u16)t;
    }
    __syncthreads();  // B3: s_ord ready

    // ---- folded MLP: z = sum p*W_fold + zc ; sigmoid ----
    float zp = 0.f;
    for (int p = t; p < KP * HC; p += 512) {
        int i = p >> 6, c = p & 63;
        int nn = s_ord[i];
        zp += H2[nn * SP + c] * wf[WF_FOLD + p];
    }
    #pragma unroll
    for (int off = 32; off > 0; off >>= 1) zp += __shfl_down(zp, off);
    if ((t & 63) == 0) s_red[t >> 6] = zp;
    __syncthreads();  // B4
    if (t == 0) {
        float z = wf[WF_ZC];
        #pragma unroll
        for (int i = 0; i < 8; ++i) z += s_red[i];
        float sg = 1.0f / (1.0f + expf(-z));
        if (isf32) ((float*)dout)[g] = sg;
        else       ((u16*)dout)[g]   = f2bf(sg);
    }
}

extern "C" void kernel_launch(void* const* d_in, const int* in_sizes, int n_in,
                              void* d_out, int out_size, void* d_ws, size_t ws_size,
                              hipStream_t stream) {
    const void* x   = d_in[0];
    const int*  ei  = (const int*)d_in[1];
    const void* W1l = d_in[3];
    const void* W1r = d_in[4];
    const void* b1  = d_in[5];
    const void* W2l = d_in[6];
    const void* W2r = d_in[7];
    const void* b2  = d_in[8];
    const void* Wl1 = d_in[9];
    const void* bl1 = d_in[10];
    const void* Wl2 = d_in[11];
    const void* bl2 = d_in[12];

    char* ws    = (char*)d_ws;
    u32*  A32   = (u32*)ws;                      // 4,239,360 B (512 x 2070 u32)
    float* wf   = (float*)(ws + 4239360);        // 97,288 B (total ~4.34 MB)

    hipMemsetAsync(A32, 0, 4239360, stream);
    k_pre<<<996, 256, 0, stream>>>((const u32*)x, ei, W1l, W1r, b1, W2l, W2r, b2,
                                   Wl1, bl1, Wl2, bl2, A32, wf);
    k_fused<<<GG, 512, 0, stream>>>(x, A32, wf, d_out);
}

// Round 6
// 179.093 us; speedup vs baseline: 1.1279x; 1.1279x over previous
//
#include <hip/hip_runtime.h>

typedef unsigned short u16;
typedef unsigned int u32;
typedef unsigned char u8;
typedef unsigned long long u64;
typedef float f32x2 __attribute__((ext_vector_type(2)));

#define GG   512
#define NPG  90
#define NTOT (GG*NPG)
#define NED  921600
#define FIN  90
#define HC   64
#define KP   70
#define AW   23      // packed-A words per row (23*4 = 92 >= 90)
#define AWG  (NPG*AW) // 2070 words per graph

#define SAD  92   // x stride (floats): 16B-aligned rows -> ds_read_b128
#define SP   68   // P/r1/P2/h2 stride: float4 rows 16B-aligned; 17l mod 32 bijective
#define APW  25   // packed-A LDS stride (words): 25l mod 32 bijective -> conflict-free b32

// wf (f32 weights in ws) layout, float offsets:
#define WF_W1L 0
#define WF_W1R 5760
#define WF_W2L 11520
#define WF_W2R 15616
#define WF_B1  19712
#define WF_B2  19776
#define WF_FOLD 19840
#define WF_ZC  24320
#define WF_FLAG 24321

__device__ __forceinline__ float bf2f(u16 u) {
    union { u32 i; float f; } v; v.i = ((u32)u) << 16; return v.f;
}
__device__ __forceinline__ float bflo(u32 u) {
    union { u32 i; float f; } v; v.i = u << 16; return v.f;
}
__device__ __forceinline__ float bfhi(u32 u) {
    union { u32 i; float f; } v; v.i = u & 0xFFFF0000u; return v.f;
}
__device__ __forceinline__ u16 f2bf(float f) {
    union { float f; u32 i; } v; v.f = f;
    u32 r = (v.i + 0x7FFFu + ((v.i >> 16) & 1u)) >> 16;
    return (u16)r;
}
__device__ __forceinline__ float ldadp(const void* p, long long i, int isf32) {
    return isf32 ? ((const float*)p)[i] : bf2f(((const u16*)p)[i]);
}
// packed IEEE fma pair (v_pk_fma_f32): bitwise == two fmaf per component
__device__ __forceinline__ f32x2 pkfma(f32x2 a, f32x2 b, f32x2 c) {
    return __builtin_elementwise_fma(a, b, c);
}
__device__ __forceinline__ f32x2 s2(float x) { return (f32x2){x, x}; }

// ---- merged prep: byte-packed dense-A build + weight convert + MLP fold. (unchanged)
__global__ __launch_bounds__(256) void k_pre(
    const u32* __restrict__ xw, const int* __restrict__ ei,
    const void* W1l, const void* W1r, const void* b1,
    const void* W2l, const void* W2r, const void* b2,
    const void* Wl1, const void* bl1, const void* Wl2, const void* bl2,
    u32* __restrict__ A32, float* __restrict__ wf)
{
    __shared__ int sf;
    const int t = threadIdx.x;
    const int b = blockIdx.x;

    if (b < 900) {
        int lane = t & 63;
        u32 v = (lane < 16) ? (u32)ei[lane] : 0u;
        u64 bb = __ballot((lane & 1) && (v != 0));
        bool wide = (bb == 0ull);          // int64: odd (hi) words all zero
        int e0 = b * 1024 + t * 4;
        int s[4], d[4];
        if (wide) {
            uint4 s01 = *(const uint4*)(ei + 2 * e0);
            uint4 s23 = *(const uint4*)(ei + 2 * e0 + 4);
            uint4 d01 = *(const uint4*)(ei + 2 * (NED + e0));
            uint4 d23 = *(const uint4*)(ei + 2 * (NED + e0) + 4);
            s[0] = (int)s01.x; s[1] = (int)s01.z; s[2] = (int)s23.x; s[3] = (int)s23.z;
            d[0] = (int)d01.x; d[1] = (int)d01.z; d[2] = (int)d23.x; d[3] = (int)d23.z;
        } else {
            uint4 ss = *(const uint4*)(ei + e0);
            uint4 dd = *(const uint4*)(ei + NED + e0);
            s[0] = (int)ss.x; s[1] = (int)ss.y; s[2] = (int)ss.z; s[3] = (int)ss.w;
            d[0] = (int)dd.x; d[1] = (int)dd.y; d[2] = (int)dd.z; d[3] = (int)dd.w;
        }
        #pragma unroll
        for (int k = 0; k < 4; ++k) {
            int dk = d[k];
            if ((unsigned)dk >= NTOT) continue;
            int g = (unsigned)dk / NPG;
            int dl = dk - g * NPG;
            int ls = s[k] - g * NPG;
            if ((unsigned)ls >= NPG) continue;
            atomicAdd(&A32[(size_t)g * AWG + dl * AW + (ls >> 2)],
                      1u << (8 * (ls & 3)));
        }
        return;
    }

    if (t < 64) {
        u32 e = (xw[t] >> 7) & 0xFF;       // exponent of low-half-as-bf16
        u64 bb = __ballot(e >= 136);       // impossible for N(0,1)-scale bf16
        if (t == 0) sf = (bb != 0ull) ? 1 : 0;
    }
    __syncthreads();
    const int f32 = sf;

    if (b < 978) {
        int i = (b - 900) * 256 + t;
        if      (i < 5760)  wf[i] = ldadp(W1l, i, f32);
        else if (i < 11520) wf[i] = ldadp(W1r, i - 5760, f32);
        else if (i < 15616) wf[i] = ldadp(W2l, i - 11520, f32);
        else if (i < 19712) wf[i] = ldadp(W2r, i - 15616, f32);
        else if (i < 19776) wf[i] = ldadp(b1, i - 19712, f32);
        else if (i < 19840) wf[i] = ldadp(b2, i - 19776, f32);
        if (b == 900 && t == 0) wf[WF_FLAG] = f32 ? 1.0f : 0.0f;
    } else {
        int m = (b - 978) * 256 + t;
        if (m < 4480) {
            float s = 0.f;
            if (!f32) {
                // vectorized bf16 loads; multiply/add sequence identical to scalar path
                const uint4* Wp = (const uint4*)((const u16*)Wl1 + (size_t)m * HC);
                #pragma unroll
                for (int q = 0; q < 8; ++q) {
                    uint4 v = Wp[q];
                    u32 a0 = v.x, a1 = v.y, a2 = v.z, a3 = v.w;
                    int j = q * 8;
                    s += bflo(a0) * bf2f(((const u16*)Wl2)[j+0]);
                    s += bfhi(a0) * bf2f(((const u16*)Wl2)[j+1]);
                    s += bflo(a1) * bf2f(((const u16*)Wl2)[j+2]);
                    s += bfhi(a1) * bf2f(((const u16*)Wl2)[j+3]);
                    s += bflo(a2) * bf2f(((const u16*)Wl2)[j+4]);
                    s += bfhi(a2) * bf2f(((const u16*)Wl2)[j+5]);
                    s += bflo(a3) * bf2f(((const u16*)Wl2)[j+6]);
                    s += bfhi(a3) * bf2f(((const u16*)Wl2)[j+7]);
                }
            } else {
                for (int j = 0; j < HC; ++j)
                    s += ((const float*)Wl1)[(long long)m * HC + j] * ((const float*)Wl2)[j];
            }
            wf[WF_FOLD + m] = s;
        } else if (m == 4480) {
            float s = ldadp(bl2, 0, f32);
            for (int j = 0; j < HC; ++j)
                s += ldadp(bl1, j, f32) * ldadp(Wl2, j, f32);
            wf[WF_ZC] = s;
        }
    }
}

// ---- fused pipeline: round-4 structure (7 barriers, region rotation) with
// packed-f32 math: acc/weight/value pairs over adjacent output columns (j,j+1)
// -> v_pk_fma_f32 halves VALU instructions; per-component chains unchanged
// (same ascending-k fma order) -> bitwise-identical output.
// LDS regions (bytes):
//   As/RG2 @0      33120  (x [90][92] during GEMM1; then r1 -> h2 [90][68])
//   R1     @33120  24480  (P -> P2 [90][68])
//   Apk    @57600   9000  (packed A bytes [90][25], whole kernel)
//   key/red/ord @66600 ~540
__global__ __launch_bounds__(512, 4) void k_fused(
    const void* __restrict__ x, const u32* __restrict__ A32,
    const float* __restrict__ wf, void* __restrict__ dout)
{
    __shared__ __align__(16) char smem[67136];
    float* As    = (float*)smem;                 // x during GEMM1
    float* RG2   = (float*)smem;                 // r1, then h2 (stride SP)
    float* R1    = (float*)(smem + 33120);       // P, then P2 (stride SP)
    u32*   Apk   = (u32*)(smem + 57600);
    float* s_key = (float*)(smem + 66600);
    float* s_red = (float*)(smem + 66960);
    u16*   s_ord = (u16*)(smem + 66992);

    const int g = blockIdx.x;
    const int t = threadIdx.x;
    const bool isf32 = (wf[WF_FLAG] > 0.5f);

    const int l = t & 63;
    const int w = __builtin_amdgcn_readfirstlane(t >> 6);  // wave id, SGPR
    const int jb = w * 8;                                   // wave-uniform slab
    const int row0 = l;
    const bool has2 = (l < NPG - 64);
    const int row1 = has2 ? l + 64 : l;

    // ---- load packed A and stage to LDS ----
    u32 abuf[5];
    {
        const u32* Ag = A32 + (size_t)g * AWG;
        #pragma unroll
        for (int j = 0; j < 5; ++j) {
            int p = t + j * 512;
            abuf[j] = (p < AWG) ? Ag[p] : 0u;
        }
    }

    // ---- stage x -> As (expand bf16 to f32; single GEMM path) ----
    if (isf32) {
        const float* xg = (const float*)x + (size_t)g * 8100;
        for (int p = t; p < 8100; p += 512) {
            int r = p / NPG, c = p - r * NPG;
            As[r * SAD + c] = xg[p];
        }
    } else {
        const u32* xg = (const u32*)((const u16*)x + (size_t)g * 8100);
        for (int p = t; p < 4050; p += 512) {
            int r = p / 45, c = (p - r * 45) * 2;
            u32 v = xg[p];
            As[r * SAD + c]     = bflo(v);
            As[r * SAD + c + 1] = bfhi(v);
        }
    }
    if (t < 180) As[(t >> 1) * SAD + 90 + (t & 1)] = 0.f;  // pad cols -> exact +0
    #pragma unroll
    for (int j = 0; j < 5; ++j) {
        int p = t + j * 512;
        if (p < AWG) {
            int r = p / AW, wc = p - r * AW;
            Apk[r * APW + wc] = abuf[j];
        }
    }
    __syncthreads();  // B0: x + Apk staged

    // ---- GEMM1: P = x@W1l, Q = x@W1r + b1 ; packed pairs over (j,j+1) ----
    f32x2 accP[2][4], accQ[2][4];
    {
        const f32x2* bb = (const f32x2*)(wf + WF_B1 + jb);
        #pragma unroll
        for (int jp = 0; jp < 4; ++jp) {
            f32x2 bv = bb[jp];
            accP[0][jp] = (f32x2){0.f, 0.f}; accP[1][jp] = (f32x2){0.f, 0.f};
            accQ[0][jp] = bv;                accQ[1][jp] = bv;
        }
    }
    {
        const float* WL = wf + WF_W1L + jb;
        const float* WR = wf + WF_W1R + jb;
        const float* X0 = As + row0 * SAD;
        const float* X1 = As + row1 * SAD;
        for (int k0 = 0; k0 < 23; ++k0) {   // k=90,91: x=0 -> exact +0 (w reads in-bounds of wf)
            float4 q0 = *(const float4*)(X0 + 4 * k0);
            float4 q1 = *(const float4*)(X1 + 4 * k0);
            float xa0[4] = {q0.x, q0.y, q0.z, q0.w};
            float xa1[4] = {q1.x, q1.y, q1.z, q1.w};
            #pragma unroll
            for (int jj = 0; jj < 4; ++jj) {
                int k = 4 * k0 + jj;
                const f32x2* wl2 = (const f32x2*)(WL + k * HC);  // wave-uniform SGPR pairs
                const f32x2* wr2 = (const f32x2*)(WR + k * HC);
                f32x2 m0 = s2(xa0[jj]), m1 = s2(xa1[jj]);
                #pragma unroll
                for (int jp = 0; jp < 4; ++jp) {
                    f32x2 wl = wl2[jp], wr = wr2[jp];
                    accP[0][jp] = pkfma(m0, wl, accP[0][jp]);
                    accQ[0][jp] = pkfma(m0, wr, accQ[0][jp]);
                    accP[1][jp] = pkfma(m1, wl, accP[1][jp]);
                    accQ[1][jp] = pkfma(m1, wr, accQ[1][jp]);
                }
            }
        }
    }

    // ---- write P (no barrier needed: R1 disjoint from As; staging done at B0) ----
    *(float4*)(R1 + row0 * SP + jb)     = make_float4(accP[0][0].x, accP[0][0].y, accP[0][1].x, accP[0][1].y);
    *(float4*)(R1 + row0 * SP + jb + 4) = make_float4(accP[0][2].x, accP[0][2].y, accP[0][3].x, accP[0][3].y);
    if (has2) {
        *(float4*)(R1 + row1 * SP + jb)     = make_float4(accP[1][0].x, accP[1][0].y, accP[1][1].x, accP[1][1].y);
        *(float4*)(R1 + row1 * SP + jb + 4) = make_float4(accP[1][2].x, accP[1][2].y, accP[1][3].x, accP[1][3].y);
    }
    __syncthreads();  // B2: P complete (and all As reads finished)

    // ---- Agg1: h1 = rc*(A@P) + Q ; packed pairs; rc from in-loop sum ----
    f32x2 r1v[2][4];
    float rc0, rc1;
    {
        f32x2 acc[2][4];
        float asum0 = 0.f, asum1 = 0.f;
        #pragma unroll
        for (int i = 0; i < 2; ++i)
            #pragma unroll
            for (int jp = 0; jp < 4; ++jp) acc[i][jp] = (f32x2){0.f, 0.f};
        const u32* A0 = Apk + row0 * APW;
        const u32* A1 = Apk + row1 * APW;
        for (int k0 = 0; k0 < 22; ++k0) {
            u32 w0 = A0[k0], w1 = A1[k0];
            #pragma unroll
            for (int jj = 0; jj < 4; ++jj) {
                int k = 4 * k0 + jj;
                float4 p0 = *(const float4*)(R1 + k * SP + jb);     // broadcast
                float4 p1 = *(const float4*)(R1 + k * SP + jb + 4);
                f32x2 pv[4] = {(f32x2){p0.x,p0.y}, (f32x2){p0.z,p0.w},
                               (f32x2){p1.x,p1.y}, (f32x2){p1.z,p1.w}};
                float a0 = (float)((w0 >> (8 * jj)) & 255u);
                float a1 = (float)((w1 >> (8 * jj)) & 255u);
                asum0 += a0; asum1 += a1;
                f32x2 a0s = s2(a0), a1s = s2(a1);
                #pragma unroll
                for (int jp = 0; jp < 4; ++jp) {
                    acc[0][jp] = pkfma(a0s, pv[jp], acc[0][jp]);
                    acc[1][jp] = pkfma(a1s, pv[jp], acc[1][jp]);
                }
            }
        }
        {   // tail k = 88, 89
            u32 w0 = A0[22], w1 = A1[22];
            #pragma unroll
            for (int jj = 0; jj < 2; ++jj) {
                int k = 88 + jj;
                float4 p0 = *(const float4*)(R1 + k * SP + jb);
                float4 p1 = *(const float4*)(R1 + k * SP + jb + 4);
                f32x2 pv[4] = {(f32x2){p0.x,p0.y}, (f32x2){p0.z,p0.w},
                               (f32x2){p1.x,p1.y}, (f32x2){p1.z,p1.w}};
                float a0 = (float)((w0 >> (8 * jj)) & 255u);
                float a1 = (float)((w1 >> (8 * jj)) & 255u);
                asum0 += a0; asum1 += a1;
                f32x2 a0s = s2(a0), a1s = s2(a1);
                #pragma unroll
                for (int jp = 0; jp < 4; ++jp) {
                    acc[0][jp] = pkfma(a0s, pv[jp], acc[0][jp]);
                    acc[1][jp] = pkfma(a1s, pv[jp], acc[1][jp]);
                }
            }
        }
        rc0 = 1.0f / fmaxf(asum0, 1.0f);
        rc1 = 1.0f / fmaxf(asum1, 1.0f);
        #pragma unroll
        for (int i = 0; i < 2; ++i) {
            if (i == 0 || has2) {
                int n = i ? row1 : row0;
                float rc = i ? rc1 : rc0;
                f32x2 rcs = s2(rc);
                f32x2 h[4];
                #pragma unroll
                for (int jp = 0; jp < 4; ++jp) h[jp] = pkfma(rcs, acc[i][jp], accQ[i][jp]);
                size_t base = 512 + (size_t)(g * NPG + n) * HC + jb;
                if (isf32) {
                    *(float4*)((float*)dout + base)     = make_float4(h[0].x, h[0].y, h[1].x, h[1].y);
                    *(float4*)((float*)dout + base + 4) = make_float4(h[2].x, h[2].y, h[3].x, h[3].y);
                } else {
                    uint4 pk;
                    pk.x = (u32)f2bf(h[0].x) | ((u32)f2bf(h[0].y) << 16);
                    pk.y = (u32)f2bf(h[1].x) | ((u32)f2bf(h[1].y) << 16);
                    pk.z = (u32)f2bf(h[2].x) | ((u32)f2bf(h[2].y) << 16);
                    pk.w = (u32)f2bf(h[3].x) | ((u32)f2bf(h[3].y) << 16);
                    *(uint4*)((u16*)dout + base) = pk;
                }
                #pragma unroll
                for (int jp = 0; jp < 4; ++jp)
                    r1v[i][jp] = (f32x2){fmaxf(h[jp].x, 0.f), fmaxf(h[jp].y, 0.f)};
            }
        }
    }
    // ---- write r1 -> RG2 (x region, dead since B2; no extra barrier needed) ----
    *(float4*)(RG2 + row0 * SP + jb)     = make_float4(r1v[0][0].x, r1v[0][0].y, r1v[0][1].x, r1v[0][1].y);
    *(float4*)(RG2 + row0 * SP + jb + 4) = make_float4(r1v[0][2].x, r1v[0][2].y, r1v[0][3].x, r1v[0][3].y);
    if (has2) {
        *(float4*)(RG2 + row1 * SP + jb)     = make_float4(r1v[1][0].x, r1v[1][0].y, r1v[1][1].x, r1v[1][1].y);
        *(float4*)(RG2 + row1 * SP + jb + 4) = make_float4(r1v[1][2].x, r1v[1][2].y, r1v[1][3].x, r1v[1][3].y);
    }
    __syncthreads();  // B3: r1 complete; P reads done

    // ---- GEMM2: P2 = r1@W2l, Q2 = r1@W2r + b2 ; packed pairs ----
    {
        const f32x2* bb = (const f32x2*)(wf + WF_B2 + jb);
        #pragma unroll
        for (int jp = 0; jp < 4; ++jp) {
            f32x2 bv = bb[jp];
            accP[0][jp] = (f32x2){0.f, 0.f}; accP[1][jp] = (f32x2){0.f, 0.f};
            accQ[0][jp] = bv;                accQ[1][jp] = bv;
        }
    }
    {
        const float* WL = wf + WF_W2L + jb;
        const float* WR = wf + WF_W2R + jb;
        const float* V0 = RG2 + row0 * SP;
        const float* V1 = RG2 + row1 * SP;
        for (int k0 = 0; k0 < 16; ++k0) {
            float4 q0 = *(const float4*)(V0 + 4 * k0);
            float4 q1 = *(const float4*)(V1 + 4 * k0);
            float va0[4] = {q0.x, q0.y, q0.z, q0.w};
            float va1[4] = {q1.x, q1.y, q1.z, q1.w};
            #pragma unroll
            for (int jj = 0; jj < 4; ++jj) {
                int k = 4 * k0 + jj;
                const f32x2* wl2 = (const f32x2*)(WL + k * HC);
                const f32x2* wr2 = (const f32x2*)(WR + k * HC);
                f32x2 m0 = s2(va0[jj]), m1 = s2(va1[jj]);
                #pragma unroll
                for (int jp = 0; jp < 4; ++jp) {
                    f32x2 wl = wl2[jp], wr = wr2[jp];
                    accP[0][jp] = pkfma(m0, wl, accP[0][jp]);
                    accQ[0][jp] = pkfma(m0, wr, accQ[0][jp]);
                    accP[1][jp] = pkfma(m1, wl, accP[1][jp]);
                    accQ[1][jp] = pkfma(m1, wr, accQ[1][jp]);
                }
            }
        }
    }
    // ---- write P2 -> R1 (P dead: all waves passed B3 => P reads finished) ----
    *(float4*)(R1 + row0 * SP + jb)     = make_float4(accP[0][0].x, accP[0][0].y, accP[0][1].x, accP[0][1].y);
    *(float4*)(R1 + row0 * SP + jb + 4) = make_float4(accP[0][2].x, accP[0][2].y, accP[0][3].x, accP[0][3].y);
    if (has2) {
        *(float4*)(R1 + row1 * SP + jb)     = make_float4(accP[1][0].x, accP[1][0].y, accP[1][1].x, accP[1][1].y);
        *(float4*)(R1 + row1 * SP + jb + 4) = make_float4(accP[1][2].x, accP[1][2].y, accP[1][3].x, accP[1][3].y);
    }
    __syncthreads();  // B4: P2 complete; r1 reads done

    // ---- Agg2: h2 = rc*(A@P2) + Q2 ; key = col 63 ----
    f32x2 h2v[2][4];
    {
        f32x2 acc[2][4];
        #pragma unroll
        for (int i = 0; i < 2; ++i)
            #pragma unroll
            for (int jp = 0; jp < 4; ++jp) acc[i][jp] = (f32x2){0.f, 0.f};
        const u32* A0 = Apk + row0 * APW;
        const u32* A1 = Apk + row1 * APW;
        for (int k0 = 0; k0 < 22; ++k0) {
            u32 w0 = A0[k0], w1 = A1[k0];
            #pragma unroll
            for (int jj = 0; jj < 4; ++jj) {
                int k = 4 * k0 + jj;
                float4 p0 = *(const float4*)(R1 + k * SP + jb);
                float4 p1 = *(const float4*)(R1 + k * SP + jb + 4);
                f32x2 pv[4] = {(f32x2){p0.x,p0.y}, (f32x2){p0.z,p0.w},
                               (f32x2){p1.x,p1.y}, (f32x2){p1.z,p1.w}};
                float a0 = (float)((w0 >> (8 * jj)) & 255u);
                float a1 = (float)((w1 >> (8 * jj)) & 255u);
                f32x2 a0s = s2(a0), a1s = s2(a1);
                #pragma unroll
                for (int jp = 0; jp < 4; ++jp) {
                    acc[0][jp] = pkfma(a0s, pv[jp], acc[0][jp]);
                    acc[1][jp] = pkfma(a1s, pv[jp], acc[1][jp]);
                }
            }
        }
        {   // tail k = 88, 89
            u32 w0 = A0[22], w1 = A1[22];
            #pragma unroll
            for (int jj = 0; jj < 2; ++jj) {
                int k = 88 + jj;
                float4 p0 = *(const float4*)(R1 + k * SP + jb);
                float4 p1 = *(const float4*)(R1 + k * SP + jb + 4);
                f32x2 pv[4] = {(f32x2){p0.x,p0.y}, (f32x2){p0.z,p0.w},
                               (f32x2){p1.x,p1.y}, (f32x2){p1.z,p1.w}};
                float a0 = (float)((w0 >> (8 * jj)) & 255u);
                float a1 = (float)((w1 >> (8 * jj)) & 255u);
                f32x2 a0s = s2(a0), a1s = s2(a1);
                #pragma unroll
                for (int jp = 0; jp < 4; ++jp) {
                    acc[0][jp] = pkfma(a0s, pv[jp], acc[0][jp]);
                    acc[1][jp] = pkfma(a1s, pv[jp], acc[1][jp]);
                }
            }
        }
        #pragma unroll
        for (int i = 0; i < 2; ++i) {
            if (i == 0 || has2) {
                int n = i ? row1 : row0;
                float rc = i ? rc1 : rc0;
                f32x2 rcs = s2(rc);
                #pragma unroll
                for (int jp = 0; jp < 4; ++jp)
                    h2v[i][jp] = pkfma(rcs, acc[i][jp], accQ[i][jp]);
                if (w == 7) s_key[n] = h2v[i][3].y;
            }
        }
    }
    // ---- write h2 -> RG2 (r1 dead: all waves passed B4 => GEMM2 reads finished) ----
    *(float4*)(RG2 + row0 * SP + jb)     = make_float4(h2v[0][0].x, h2v[0][0].y, h2v[0][1].x, h2v[0][1].y);
    *(float4*)(RG2 + row0 * SP + jb + 4) = make_float4(h2v[0][2].x, h2v[0][2].y, h2v[0][3].x, h2v[0][3].y);
    if (has2) {
        *(float4*)(RG2 + row1 * SP + jb)     = make_float4(h2v[1][0].x, h2v[1][0].y, h2v[1][1].x, h2v[1][1].y);
        *(float4*)(RG2 + row1 * SP + jb + 4) = make_float4(h2v[1][2].x, h2v[1][2].y, h2v[1][3].x, h2v[1][3].y);
    }
    __syncthreads();  // B5: h2 + s_key complete; P2 reads done

    // ---- stable descending rank (== stable argsort(-key)) ----
    if (t < NPG) {
        float my = s_key[t];
        int r = 0;
        for (int m2 = 0; m2 < NPG; ++m2) {
            float km = s_key[m2];
            r += (km > my) || (km == my && m2 < t);
        }
        if (r < KP) s_ord[r] = (u16)t;
    }
    __syncthreads();  // B6: s_ord ready

    // ---- folded MLP: z = sum p*W_fold + zc ; sigmoid ----
    float zp = 0.f;
    for (int p = t; p < KP * HC; p += 512) {
        int i = p >> 6, c = p & 63;
        int nn = s_ord[i];
        zp += RG2[nn * SP + c] * wf[WF_FOLD + p];
    }
    #pragma unroll
    for (int off = 32; off > 0; off >>= 1) zp += __shfl_down(zp, off);
    if ((t & 63) == 0) s_red[t >> 6] = zp;
    __syncthreads();  // B7
    if (t == 0) {
        float z = wf[WF_ZC];
        #pragma unroll
        for (int i = 0; i < 8; ++i) z += s_red[i];
        float sg = 1.0f / (1.0f + expf(-z));
        if (isf32) ((float*)dout)[g] = sg;
        else       ((u16*)dout)[g]   = f2bf(sg);
    }
}

extern "C" void kernel_launch(void* const* d_in, const int* in_sizes, int n_in,
                              void* d_out, int out_size, void* d_ws, size_t ws_size,
                              hipStream_t stream) {
    const void* x   = d_in[0];
    const int*  ei  = (const int*)d_in[1];
    const void* W1l = d_in[3];
    const void* W1r = d_in[4];
    const void* b1  = d_in[5];
    const void* W2l = d_in[6];
    const void* W2r = d_in[7];
    const void* b2  = d_in[8];
    const void* Wl1 = d_in[9];
    const void* bl1 = d_in[10];
    const void* Wl2 = d_in[11];
    const void* bl2 = d_in[12];

    char* ws    = (char*)d_ws;
    u32*  A32   = (u32*)ws;                      // 4,239,360 B (512 x 2070 u32)
    float* wf   = (float*)(ws + 4239360);        // 97,288 B (total ~4.34 MB)

    hipMemsetAsync(A32, 0, 4239360, stream);
    k_pre<<<996, 256, 0, stream>>>((const u32*)x, ei, W1l, W1r, b1, W2l, W2r, b2,
                                   Wl1, bl1, Wl2, bl2, A32, wf);
    k_fused<<<GG, 512, 0, stream>>>(x, A32, wf, d_out);
}